// Round 2
// baseline (116.953 us; speedup 1.0000x reference)
//
#include <hip/hip_runtime.h>

#define B_ROWS 131072
#define NA 16
#define DD 513
#define ALPHA 0.1f
#define EPSV 1e-7f
#define PITCH 17

__global__ __launch_bounds__(256, 2)
void hfield_kernel(const float* __restrict__ x,
                   const float* __restrict__ anc,
                   float* __restrict__ out) {
    __shared__ float redbuf[4][64 * PITCH];   // per-wave transpose buffer

    const int tid  = threadIdx.x;
    const int lane = tid & 63;
    const int wid  = tid >> 6;
    const int gw   = blockIdx.x * 4 + wid;    // global wave id
    const int TW   = gridDim.x * 4;           // total waves

    // per-lane anchor slice: Areg[a][j] = anc_spatial[a][lane + 64j]
    float Areg[NA][8];
#pragma unroll
    for (int a = 0; a < NA; ++a)
#pragma unroll
        for (int j = 0; j < 8; ++j)
            Areg[a][j] = anc[a * DD + 1 + lane + 64 * j];

    // PIN anchors in VGPRs: opaque def defeats rematerialization / spill.
#pragma unroll
    for (int a = 0; a < NA; ++a)
#pragma unroll
        for (int j = 0; j < 8; ++j)
            asm volatile("" : "+v"(Areg[a][j]));

    float* wb = redbuf[wid];
    const int g     = lane >> 4;
    const int amine = lane & 15;

    // ---- af0 for anchor (lane&15): sqrt(1 + sum(sp^2)) ----
    float af0;
    {
        float q[NA];
#pragma unroll
        for (int a = 0; a < NA; ++a) {
            float s = 0.f;
#pragma unroll
            for (int j = 0; j < 8; ++j) s = fmaf(Areg[a][j], Areg[a][j], s);
            q[a] = s;
        }
#pragma unroll
        for (int i = 0; i < NA; ++i) wb[lane * PITCH + i] = q[i];
        asm volatile("s_waitcnt lgkmcnt(0)" ::: "memory");
        float t = 0.f;
#pragma unroll
        for (int k = 0; k < 16; ++k) t += wb[(g + 4 * k) * PITCH + amine];
        t += __shfl_xor(t, 16);
        t += __shfl_xor(t, 32);
        af0 = sqrtf(1.0f + t);
    }

    const float thmin = 1.0f + 1e-7f;

    int row = gw;
    float xn[8], x0n = 0.f;
    if (row < B_ROWS) {
        const float* rp = x + (size_t)row * DD;
        x0n = rp[0];
#pragma unroll
        for (int j = 0; j < 8; ++j) xn[j] = rp[1 + lane + 64 * j];
    }

    for (; row < B_ROWS; row += TW) {
        float xc[8];
        const float x0 = x0n;
#pragma unroll
        for (int j = 0; j < 8; ++j) xc[j] = xn[j];

        // prefetch next row early (issue before the VALU-heavy dot section)
        const int nrow = row + TW;
        if (nrow < B_ROWS) {
            const float* rp = x + (size_t)nrow * DD;
            x0n = rp[0];
#pragma unroll
            for (int j = 0; j < 8; ++j) xn[j] = rp[1 + lane + 64 * j];
        }

        // per-lane partial dots (spatial part)
        float q[NA];
#pragma unroll
        for (int a = 0; a < NA; ++a) {
            float s = 0.f;
#pragma unroll
            for (int j = 0; j < 8; ++j) s = fmaf(xc[j], Areg[a][j], s);
            q[a] = s;
        }

        // wave-private LDS transpose: 64 lanes x 16 -> per-lane total for anchor (lane&15)
        // pitch 17: write banks = 17*l mod 32 (bijective over 32 lanes -> 2-way, free)
#pragma unroll
        for (int i = 0; i < NA; ++i) wb[lane * PITCH + i] = q[i];
        asm volatile("s_waitcnt lgkmcnt(0)" ::: "memory");
        float t = 0.f;
#pragma unroll
        for (int k = 0; k < 16; ++k) t += wb[(g + 4 * k) * PITCH + amine];
        t += __shfl_xor(t, 16);
        t += __shfl_xor(t, 32);

        // theta_a = x0*af0_a - spatial ; clip
        float tc = fmaxf(fmaf(x0, af0, -t), thmin);
        int   bi = amine;

        // argmin over 16 anchors, first-index tie-break
#pragma unroll
        for (int m = 1; m <= 8; m <<= 1) {
            float vo = __shfl_xor(tc, m);
            int   io = __shfl_xor(bi, m);
            bool take = (vo < tc) || (vo == tc && io < bi);
            tc = take ? vo : tc;
            bi = take ? io : bi;
        }

        // scalar epilogue (wave-uniform)
        float s2   = tc * tc - 1.0f;
        float rr   = sqrtf(s2);
        float ach  = __logf(tc + rr);            // arccosh
        float coef = ach / rr;
        float vn   = sqrtf(fmaxf(ALPHA * ALPHA * ach * ach, EPSV));
        float e    = __expf(vn);
        float ei   = 1.0f / e;
        float ch   = 0.5f * (e + ei);
        float sh   = 0.5f * (e - ei);
        float c2   = ALPHA * coef * (sh / vn);
        float c1   = fmaf(-c2, tc, ch);

        // y from pinned registers via wave-uniform scalar switch
        const int bis = __builtin_amdgcn_readfirstlane(bi);
        float y[8];
        switch (bis) {
#define YCASE(A) case A: _Pragma("unroll") for (int j = 0; j < 8; ++j) y[j] = Areg[A][j]; break;
            YCASE(0)  YCASE(1)  YCASE(2)  YCASE(3)
            YCASE(4)  YCASE(5)  YCASE(6)  YCASE(7)
            YCASE(8)  YCASE(9)  YCASE(10) YCASE(11)
            YCASE(12) YCASE(13) YCASE(14) YCASE(15)
#undef YCASE
        }

        float* op = out + (size_t)row * DD;
#pragma unroll
        for (int j = 0; j < 8; ++j)
            __builtin_nontemporal_store(fmaf(c2, y[j], c1 * xc[j]), &op[1 + lane + 64 * j]);

        float y0   = __shfl(af0, bis);           // af0 of winning anchor
        float out0 = fmaf(c2, y0, c1 * x0);
        if (lane == 0) __builtin_nontemporal_store(out0, &op[0]);
    }
}

extern "C" void kernel_launch(void* const* d_in, const int* in_sizes, int n_in,
                              void* d_out, int out_size, void* d_ws, size_t ws_size,
                              hipStream_t stream) {
    const float* x   = (const float*)d_in[0];
    const float* anc = (const float*)d_in[1];
    float* out       = (float*)d_out;
    hipLaunchKernelGGL(hfield_kernel, dim3(1024), dim3(256), 0, stream, x, anc, out);
}